// Round 12
// baseline (392.656 us; speedup 1.0000x reference)
//
#include <hip/hip_runtime.h>
#include <math.h>

#define B_TOTAL 2048
#define T_LEN   512
#define IN_D    6
#define HID     64
#define LAT     16
#define ROWS    2          // batch rows per block -> M-tile rows {0,4}: quads 0,1 valid
#define THREADS 256        // 4 waves; wave w owns output units j in [16w,16w+16) for all 3 gates
#define ASTRIDE 104        // A row stride in bf16 elems (208B = 13x16B aligned)

typedef __attribute__((ext_vector_type(8))) short bfrag;   // 8 bf16 = 4 VGPRs
typedef __attribute__((ext_vector_type(4))) float ffrag;   // 4 fp32 acc

#if __has_builtin(__builtin_amdgcn_exp2f)
#define EXP2F(x) __builtin_amdgcn_exp2f(x)
#else
#define EXP2F(x) exp2f(x)
#endif
#if __has_builtin(__builtin_amdgcn_rcpf)
#define RCPF(x) __builtin_amdgcn_rcpf(x)
#else
#define RCPF(x) (1.0f / (x))
#endif
#define MFMA16(A, B, C) __builtin_amdgcn_mfma_f32_16x16x32_bf16((A), (B), (C), 0, 0, 0)

__device__ __forceinline__ float fast_sigmoid(float x){
    return RCPF(1.0f + EXP2F(-1.44269504088896340736f * x));
}
__device__ __forceinline__ float fast_tanh(float x){
    return 1.0f - 2.0f * RCPF(EXP2F(2.88539008177792681472f * x) + 1.0f);
}
__device__ __forceinline__ unsigned short f2bf_rne(float f){
    unsigned u = __float_as_uint(f);
    return (unsigned short)((u + 0x7fffu + ((u >> 16) & 1u)) >> 16);
}

extern "C" __global__ void
__attribute__((amdgpu_flat_work_group_size(THREADS, THREADS), amdgpu_waves_per_eu(4, 4)))
glsde_kernel(const float* __restrict__ x,
             const float* __restrict__ eWih, const float* __restrict__ eWhh,
             const float* __restrict__ ebih, const float* __restrict__ ebhh,
             const float* __restrict__ muW,  const float* __restrict__ mub,
             const float* __restrict__ lvW,  const float* __restrict__ lvb,
             const float* __restrict__ oW,   const float* __restrict__ ob,
             const float* __restrict__ dfW,  const float* __restrict__ dfb,
             const float* __restrict__ dWih, const float* __restrict__ dWhh,
             const float* __restrict__ dbih, const float* __restrict__ dbhh,
             float* __restrict__ out)
{
    // Whole x slice for this block, bf16, pre-formatted as kt=2 A-fragments:
    // xstage[t][b][0..5] = x(b, t, d), [6..7] = 0.  16 KB.
    __shared__ __align__(16) unsigned short xstage[T_LEN][ROWS][8];
    __shared__ __align__(16) unsigned short Abuf[2][16][ASTRIDE];  // [buf][m][k] bf16 (h part)
    __shared__ float hfp[ROWS][HID];
    __shared__ float zsh[ROWS][LAT];
    __shared__ float zdsh[ROWS][HID];
    __shared__ float xgdsh[ROWS][3];

    const int tid  = threadIdx.x;
    const int wave = tid >> 6;
    const int lane = tid & 63;
    const int nloc = lane & 15;
    const int quad = lane >> 4;
    const int mA   = lane & 15;
    const int j    = wave * 16 + nloc;   // output unit 0..63
    const int b0   = blockIdx.x * ROWS;

    const float S1 = 1.44269504088896340736f;  // log2(e): sigmoid via exp2
    const float S2 = 2.0f * S1;                // tanh via exp2(2x)

    // ---- weights (pre-scaled by S1/S2) -> registers, plain bf16, loaded ONCE ----
    bfrag Br[3], Bz[3], Bnh[2], Bnx;
    {
        const float* wr  = eWhh + (size_t)(      j) * HID;
        const float* wz  = eWhh + (size_t)( 64 + j) * HID;
        const float* wn  = eWhh + (size_t)(128 + j) * HID;
        #pragma unroll
        for (int kt = 0; kt < 2; ++kt){
            const int o = kt * 32 + quad * 8;
            #pragma unroll
            for (int e = 0; e < 8; ++e){
                Br[kt][e]  = (short)f2bf_rne(wr[o+e] * S1);
                Bz[kt][e]  = (short)f2bf_rne(wz[o+e] * S1);
                Bnh[kt][e] = (short)f2bf_rne(wn[o+e] * S2);
            }
        }
        const float* ir  = eWih + (size_t)(      j) * IN_D;
        const float* iz  = eWih + (size_t)( 64 + j) * IN_D;
        const float* inn = eWih + (size_t)(128 + j) * IN_D;
        #pragma unroll
        for (int e = 0; e < 8; ++e){
            bool v = (quad == 0 && e < IN_D);
            Br[2][e] = v ? (short)f2bf_rne(ir[e]  * S1) : (short)0;
            Bz[2][e] = v ? (short)f2bf_rne(iz[e]  * S1) : (short)0;
            Bnx[e]   = v ? (short)f2bf_rne(inn[e] * S2) : (short)0;
        }
    }
    const float bias_r = (ebih[j]      + ebhh[j])      * S1;
    const float bias_z = (ebih[64 + j] + ebhh[64 + j]) * S1;
    const float bihn2  = ebih[128 + j] * S2;
    const float bhhn2  = ebhh[128 + j] * S2;

    // ---- zero Abuf (h(0)=0; never-written rows stay 0 forever) ----
    {
        unsigned* ap = (unsigned*)Abuf;
        for (int i = tid; i < (int)(sizeof(Abuf) / 4); i += THREADS) ap[i] = 0u;
    }

    // ---- stage ALL of x for this block into LDS (one-time) ----
    for (int idx = tid; idx < T_LEN * ROWS; idx += THREADS){
        const int tt = idx & (T_LEN - 1);
        const int bb = idx >> 9;
        const float* xr = x + (size_t)(b0 + bb) * T_LEN * IN_D + (size_t)tt * IN_D;
        const float2* p2 = (const float2*)xr;           // 8B-aligned (24B stride)
        float2 v0 = p2[0], v1 = p2[1], v2 = p2[2];
        bfrag f;
        f[0] = (short)f2bf_rne(v0.x); f[1] = (short)f2bf_rne(v0.y);
        f[2] = (short)f2bf_rne(v1.x); f[3] = (short)f2bf_rne(v1.y);
        f[4] = (short)f2bf_rne(v2.x); f[5] = (short)f2bf_rne(v2.y);
        f[6] = 0; f[7] = 0;
        *(bfrag*)&xstage[tt][bb][0] = f;
    }
    __syncthreads();

    // lane (quad, j): quad 0 -> batch row 0 (M row 0), quad 1 -> batch row 1 (M row 4).
    // Quads 2,3 compute bounded garbage (gates in (0,1)/(−1,1) keep it finite);
    // their h-writes land in D-rows nobody consumes — harmless, no divergence.
    float hreg = 0.f;

    // x A-fragment source: logical A row mA gets batch row (mA>>2)&1 (dup for others)
    const unsigned short* xsp = &xstage[0][(mA >> 2) & 1][0];

    // Ax register pipeline: Ax holds fragment for step t; AxN prefetches t+1.
    bfrag Ax = *(const bfrag*)(xsp);

#define GRU_STEP(bufR, bufW, T)                                                   \
    do {                                                                          \
        const unsigned short* ah_ = &bufR[mA][0];                                 \
        bfrag Ah0 = *(const bfrag*)(ah_ + 0  + quad * 8);                         \
        bfrag Ah1 = *(const bfrag*)(ah_ + 32 + quad * 8);                         \
        int tn_ = (T) + 1; if (tn_ >= T_LEN) tn_ = T_LEN - 1;                     \
        bfrag AxN = *(const bfrag*)(xsp + (size_t)tn_ * (ROWS * 8));              \
        ffrag aR  = {bias_r, bias_r, bias_r, bias_r};                             \
        ffrag aZ  = {bias_z, bias_z, bias_z, bias_z};                             \
        ffrag aNX = {bihn2,  bihn2,  bihn2,  bihn2 };                             \
        ffrag aNH = {bhhn2,  bhhn2,  bhhn2,  bhhn2 };                             \
        /* x-part first: Ax resident, overlaps Ah ds_read latency */              \
        aR  = MFMA16(Ax,  Br[2],  aR );                                           \
        aZ  = MFMA16(Ax,  Bz[2],  aZ );                                           \
        aNX = MFMA16(Ax,  Bnx,    aNX);                                           \
        aR  = MFMA16(Ah0, Br[0],  aR );                                           \
        aZ  = MFMA16(Ah0, Bz[0],  aZ );                                           \
        aNH = MFMA16(Ah0, Bnh[0], aNH);                                           \
        aR  = MFMA16(Ah1, Br[1],  aR );                                           \
        aZ  = MFMA16(Ah1, Bz[1],  aZ );                                           \
        aNH = MFMA16(Ah1, Bnh[1], aNH);                                           \
        float rg = RCPF(1.0f + EXP2F(-aR[0]));                                    \
        float zg = RCPF(1.0f + EXP2F(-aZ[0]));                                    \
        float yy = aNX[0] + rg * aNH[0];                                          \
        float ng = 1.0f - 2.0f * RCPF(EXP2F(yy) + 1.0f);                          \
        float hn = (1.0f - zg) * ng + zg * hreg;                                  \
        hreg = hn;                                                                \
        bufW[quad * 4][j] = f2bf_rne(hn);                                         \
        Ax = AxN;                                                                 \
        __syncthreads();                                                          \
    } while (0)

    // ================= encoder GRU: 512 steps, 1 barrier/step, NO global ops =====
    for (int t = 0; t < T_LEN; t += 2){
        GRU_STEP(Abuf[0], Abuf[1], t);
        GRU_STEP(Abuf[1], Abuf[0], t + 1);
    }
#undef GRU_STEP

    // ---- publish final h (fp32, from registers): batch row = quad (0,1 only) ----
    if (quad < ROWS) hfp[quad][j] = hreg;
    __syncthreads();

    // ================= heads: mu, logvar, z0 =================
    const int zrow = tid >> 4, zi = tid & 15;
    float z0v = 0.0f;
    if (tid < ROWS * LAT){
        float am = mub[zi], al = lvb[zi];
        const float4* pm = (const float4*)(muW + (size_t)zi * HID);
        const float4* pq = (const float4*)(lvW + (size_t)zi * HID);
        const float4* ph = (const float4*)(&hfp[zrow][0]);
        #pragma unroll
        for (int q = 0; q < 16; ++q){
            float4 wm = pm[q], wl = pq[q], hv = ph[q];
            am += wm.x*hv.x + wm.y*hv.y + wm.z*hv.z + wm.w*hv.w;
            al += wl.x*hv.x + wl.y*hv.y + wl.z*hv.z + wl.w*hv.w;
        }
        const size_t muBase = (size_t)B_TOTAL * T_LEN;
        out[muBase + (size_t)(b0 + zrow) * LAT + zi] = am;
        out[muBase + (size_t)B_TOTAL * LAT + (size_t)(b0 + zrow) * LAT + zi] = al;
        z0v = am + __expf(0.5f * al);
    }

    // ================= ODE: RK4, 24 fixed steps on [0,1] =================
    if (tid < ROWS * LAT){
        float ows[16];
        {
            const float4* pw = (const float4*)(oW + (size_t)zi * LAT);
            #pragma unroll
            for (int q = 0; q < 4; ++q){
                float4 w = pw[q];
                ows[4*q+0] = w.x; ows[4*q+1] = w.y; ows[4*q+2] = w.z; ows[4*q+3] = w.w;
            }
        }
        const float obv = ob[zi];
        float z = z0v;
        const float hstep = 1.0f / 24.0f;
        for (int s = 0; s < 24; ++s){
            float y, k1, k2, k3, k4;
            y = z;
            { float acc = obv;
              #pragma unroll
              for (int jj = 0; jj < 16; ++jj){ float yj = __shfl(y, jj, 16); acc = fmaf(ows[jj], yj, acc); }
              k1 = fmaxf(acc, 0.0f); }
            y = z + 0.5f * hstep * k1;
            { float acc = obv;
              #pragma unroll
              for (int jj = 0; jj < 16; ++jj){ float yj = __shfl(y, jj, 16); acc = fmaf(ows[jj], yj, acc); }
              k2 = fmaxf(acc, 0.0f); }
            y = z + 0.5f * hstep * k2;
            { float acc = obv;
              #pragma unroll
              for (int jj = 0; jj < 16; ++jj){ float yj = __shfl(y, jj, 16); acc = fmaf(ows[jj], yj, acc); }
              k3 = fmaxf(acc, 0.0f); }
            y = z + hstep * k3;
            { float acc = obv;
              #pragma unroll
              for (int jj = 0; jj < 16; ++jj){ float yj = __shfl(y, jj, 16); acc = fmaf(ows[jj], yj, acc); }
              k4 = fmaxf(acc, 0.0f); }
            z += (hstep / 6.0f) * (k1 + 2.0f*k2 + 2.0f*k3 + k4);
        }
        zsh[zrow][zi] = z;
    }
    __syncthreads();

    // ================= decoder fc: zd = relu(z @ dfW.T + dfb) =================
    for (int idx = tid; idx < ROWS * HID; idx += THREADS){
        const int row = idx >> 6, o = idx & 63;
        float acc = dfb[o];
        const float4* pw = (const float4*)(dfW + (size_t)o * LAT);
        const float4* pz = (const float4*)(&zsh[row][0]);
        #pragma unroll
        for (int q = 0; q < 4; ++q){
            float4 w = pw[q], zv = pz[q];
            acc += w.x*zv.x + w.y*zv.y + w.z*zv.z + w.w*zv.w;
        }
        zdsh[row][o] = fmaxf(acc, 0.0f);
    }
    __syncthreads();

    // xg_dec = zd @ dec_Wih.T + dec_bih
    if (tid < ROWS * 3){
        const int row = tid / 3, gg = tid % 3;
        float acc = dbih[gg];
        const float4* pw = (const float4*)(dWih + (size_t)gg * HID);
        const float4* pz = (const float4*)(&zdsh[row][0]);
        #pragma unroll
        for (int q = 0; q < 16; ++q){
            float4 w = pw[q], zv = pz[q];
            acc += w.x*zv.x + w.y*zv.y + w.z*zv.z + w.w*zv.w;
        }
        xgdsh[row][gg] = acc;
    }
    __syncthreads();

    // ====== decoder GRU (hidden dim 1), 512 steps, direct float4 global stores ===
    if (tid < ROWS){
        const int row = tid;
        const float xr = xgdsh[row][0], xz = xgdsh[row][1], xn = xgdsh[row][2];
        const float A0 = dWhh[0], A1 = dWhh[1], A2 = dWhh[2];
        const float c0 = dbhh[0], c1 = dbhh[1], c2 = dbhh[2];
        float* orow = out + (size_t)(b0 + row) * T_LEN;   // 16B-aligned
        float h = 0.0f;
        float ob4[4];
        for (int t = 0; t < T_LEN; ++t){
            float rr = fast_sigmoid(xr + A0 * h + c0);
            float zz = fast_sigmoid(xz + A1 * h + c1);
            float nn = fast_tanh(xn + rr * (A2 * h + c2));
            h = (1.0f - zz) * nn + zz * h;
            ob4[t & 3] = h;
            if ((t & 3) == 3) *(float4*)(orow + (t - 3)) = *(float4*)ob4;
        }
    }
}

extern "C" void kernel_launch(void* const* d_in, const int* in_sizes, int n_in,
                              void* d_out, int out_size, void* d_ws, size_t ws_size,
                              hipStream_t stream){
    glsde_kernel<<<B_TOTAL / ROWS, THREADS, 0, stream>>>(
        (const float*)d_in[0],  (const float*)d_in[1],  (const float*)d_in[2],
        (const float*)d_in[3],  (const float*)d_in[4],  (const float*)d_in[5],
        (const float*)d_in[6],  (const float*)d_in[7],  (const float*)d_in[8],
        (const float*)d_in[9],  (const float*)d_in[10], (const float*)d_in[11],
        (const float*)d_in[12], (const float*)d_in[13], (const float*)d_in[14],
        (const float*)d_in[15], (const float*)d_in[16], (float*)d_out);
}

// Round 13
// 316.934 us; speedup vs baseline: 1.2389x; 1.2389x over previous
//
#include <hip/hip_runtime.h>
#include <math.h>

#define B_TOTAL 2048
#define T_LEN   512
#define IN_D    6
#define HID     64
#define LAT     16
#define ROWS    4          // batch rows per block -> M-tile rows {0,4,8,12}: 1 row per lane quad
#define THREADS 256        // 4 waves; wave w owns output units j in [16w,16w+16) for all 3 gates
#define ASTRIDE 104        // A row stride in bf16 elems (208B = 13x16B aligned)

typedef __attribute__((ext_vector_type(8))) short bfrag;   // 8 bf16 = 4 VGPRs
typedef __attribute__((ext_vector_type(4))) float ffrag;   // 4 fp32 acc

#if __has_builtin(__builtin_amdgcn_exp2f)
#define EXP2F(x) __builtin_amdgcn_exp2f(x)
#else
#define EXP2F(x) exp2f(x)
#endif
#if __has_builtin(__builtin_amdgcn_rcpf)
#define RCPF(x) __builtin_amdgcn_rcpf(x)
#else
#define RCPF(x) (1.0f / (x))
#endif
#define MFMA16(A, B, C) __builtin_amdgcn_mfma_f32_16x16x32_bf16((A), (B), (C), 0, 0, 0)

__device__ __forceinline__ float fast_sigmoid(float x){
    return RCPF(1.0f + EXP2F(-1.44269504088896340736f * x));
}
__device__ __forceinline__ float fast_tanh(float x){
    return 1.0f - 2.0f * RCPF(EXP2F(2.88539008177792681472f * x) + 1.0f);
}
__device__ __forceinline__ unsigned short f2bf_rne(float f){
    unsigned u = __float_as_uint(f);
    return (unsigned short)((u + 0x7fffu + ((u >> 16) & 1u)) >> 16);
}

extern "C" __global__ void
__attribute__((amdgpu_flat_work_group_size(THREADS, THREADS), amdgpu_waves_per_eu(2, 2)))
glsde_kernel(const float* __restrict__ x,
             const float* __restrict__ eWih, const float* __restrict__ eWhh,
             const float* __restrict__ ebih, const float* __restrict__ ebhh,
             const float* __restrict__ muW,  const float* __restrict__ mub,
             const float* __restrict__ lvW,  const float* __restrict__ lvb,
             const float* __restrict__ oW,   const float* __restrict__ ob,
             const float* __restrict__ dfW,  const float* __restrict__ dfb,
             const float* __restrict__ dWih, const float* __restrict__ dWhh,
             const float* __restrict__ dbih, const float* __restrict__ dbhh,
             float* __restrict__ out)
{
    // Whole x slice for this block, bf16, pre-formatted as kt=2 A-fragments:
    // xstage[t][b][0..5] = x(b, t, d), [6..7] = 0.  32 KB.
    __shared__ __align__(16) unsigned short xstage[T_LEN][ROWS][8];
    __shared__ __align__(16) unsigned short Abuf[2][16][ASTRIDE];  // [buf][m][k] bf16 (h part)
    __shared__ float hfp[ROWS][HID];
    __shared__ float zsh[ROWS][LAT];
    __shared__ float zdsh[ROWS][HID];
    __shared__ float xgdsh[ROWS][3];

    const int tid  = threadIdx.x;
    const int wave = tid >> 6;
    const int lane = tid & 63;
    const int nloc = lane & 15;
    const int quad = lane >> 4;
    const int mA   = lane & 15;
    const int j    = wave * 16 + nloc;   // output unit 0..63
    const int b0   = blockIdx.x * ROWS;

    const float S1 = 1.44269504088896340736f;  // log2(e): sigmoid via exp2
    const float S2 = 2.0f * S1;                // tanh via exp2(2x)

    // ---- weights (pre-scaled by S1/S2) -> registers, plain bf16, loaded ONCE ----
    bfrag Br[3], Bz[3], Bnh[2], Bnx;
    {
        const float* wr  = eWhh + (size_t)(      j) * HID;
        const float* wz  = eWhh + (size_t)( 64 + j) * HID;
        const float* wn  = eWhh + (size_t)(128 + j) * HID;
        #pragma unroll
        for (int kt = 0; kt < 2; ++kt){
            const int o = kt * 32 + quad * 8;
            #pragma unroll
            for (int e = 0; e < 8; ++e){
                Br[kt][e]  = (short)f2bf_rne(wr[o+e] * S1);
                Bz[kt][e]  = (short)f2bf_rne(wz[o+e] * S1);
                Bnh[kt][e] = (short)f2bf_rne(wn[o+e] * S2);
            }
        }
        const float* ir  = eWih + (size_t)(      j) * IN_D;
        const float* iz  = eWih + (size_t)( 64 + j) * IN_D;
        const float* inn = eWih + (size_t)(128 + j) * IN_D;
        #pragma unroll
        for (int e = 0; e < 8; ++e){
            bool v = (quad == 0 && e < IN_D);
            Br[2][e] = v ? (short)f2bf_rne(ir[e]  * S1) : (short)0;
            Bz[2][e] = v ? (short)f2bf_rne(iz[e]  * S1) : (short)0;
            Bnx[e]   = v ? (short)f2bf_rne(inn[e] * S2) : (short)0;
        }
    }
    const float bias_r = (ebih[j]      + ebhh[j])      * S1;
    const float bias_z = (ebih[64 + j] + ebhh[64 + j]) * S1;
    const float bihn2  = ebih[128 + j] * S2;
    const float bhhn2  = ebhh[128 + j] * S2;

    // ---- zero Abuf (h(0)=0; rows not in {0,4,8,12} stay 0 forever) ----
    {
        unsigned* ap = (unsigned*)Abuf;
        for (int i = tid; i < (int)(sizeof(Abuf) / 4); i += THREADS) ap[i] = 0u;
    }

    // ---- stage ALL of x for this block into LDS (one-time) ----
    for (int idx = tid; idx < T_LEN * ROWS; idx += THREADS){
        const int tt = idx & (T_LEN - 1);
        const int bb = idx >> 9;
        const float* xr = x + (size_t)(b0 + bb) * T_LEN * IN_D + (size_t)tt * IN_D;
        const float2* p2 = (const float2*)xr;           // 8B-aligned (24B stride)
        float2 v0 = p2[0], v1 = p2[1], v2 = p2[2];
        bfrag f;
        f[0] = (short)f2bf_rne(v0.x); f[1] = (short)f2bf_rne(v0.y);
        f[2] = (short)f2bf_rne(v1.x); f[3] = (short)f2bf_rne(v1.y);
        f[4] = (short)f2bf_rne(v2.x); f[5] = (short)f2bf_rne(v2.y);
        f[6] = 0; f[7] = 0;
        *(bfrag*)&xstage[tt][bb][0] = f;
    }
    __syncthreads();

    // lane (quad, j) owns batch row quad (M row quad*4), D reg 0
    float hreg = 0.f;

    // x A-fragment source: row mA needs batch row mA>>2 (harmless dup for invalid m)
    const unsigned short* xsp = &xstage[0][mA >> 2][0];

    // Ax register pipeline: Ax holds fragment for step t; AxN prefetches t+1.
    bfrag Ax = *(const bfrag*)(xsp);

#define GRU_STEP(bufR, bufW, T)                                                   \
    do {                                                                          \
        const unsigned short* ah_ = &bufR[mA][0];                                 \
        bfrag Ah0 = *(const bfrag*)(ah_ + 0  + quad * 8);                         \
        bfrag Ah1 = *(const bfrag*)(ah_ + 32 + quad * 8);                         \
        int tn_ = (T) + 1; if (tn_ >= T_LEN) tn_ = T_LEN - 1;                     \
        bfrag AxN = *(const bfrag*)(xsp + (size_t)tn_ * (ROWS * 8));              \
        ffrag aR  = {bias_r, bias_r, bias_r, bias_r};                             \
        ffrag aZ  = {bias_z, bias_z, bias_z, bias_z};                             \
        ffrag aNX = {bihn2,  bihn2,  bihn2,  bihn2 };                             \
        ffrag aNH = {bhhn2,  bhhn2,  bhhn2,  bhhn2 };                             \
        /* x-part first: Ax resident, overlaps Ah ds_read latency */              \
        aR  = MFMA16(Ax,  Br[2],  aR );                                           \
        aZ  = MFMA16(Ax,  Bz[2],  aZ );                                           \
        aNX = MFMA16(Ax,  Bnx,    aNX);                                           \
        aR  = MFMA16(Ah0, Br[0],  aR );                                           \
        aZ  = MFMA16(Ah0, Bz[0],  aZ );                                           \
        aNH = MFMA16(Ah0, Bnh[0], aNH);                                           \
        aR  = MFMA16(Ah1, Br[1],  aR );                                           \
        aZ  = MFMA16(Ah1, Bz[1],  aZ );                                           \
        aNH = MFMA16(Ah1, Bnh[1], aNH);                                           \
        float rg = RCPF(1.0f + EXP2F(-aR[0]));                                    \
        float zg = RCPF(1.0f + EXP2F(-aZ[0]));                                    \
        float yy = aNX[0] + rg * aNH[0];                                          \
        float ng = 1.0f - 2.0f * RCPF(EXP2F(yy) + 1.0f);                          \
        float hn = (1.0f - zg) * ng + zg * hreg;                                  \
        hreg = hn;                                                                \
        bufW[quad * 4][j] = f2bf_rne(hn);                                         \
        Ax = AxN;                                                                 \
        __syncthreads();                                                          \
    } while (0)

    // ================= encoder GRU: 512 steps, 1 barrier/step, NO global ops =====
    for (int t = 0; t < T_LEN; t += 2){
        GRU_STEP(Abuf[0], Abuf[1], t);
        GRU_STEP(Abuf[1], Abuf[0], t + 1);
    }
#undef GRU_STEP

    // ---- publish final h (fp32, from registers): batch row = quad ----
    hfp[quad][j] = hreg;
    __syncthreads();

    // ================= heads: mu, logvar, z0 =================
    const int zrow = tid >> 4, zi = tid & 15;
    float z0v = 0.0f;
    if (tid < ROWS * LAT){
        float am = mub[zi], al = lvb[zi];
        const float4* pm = (const float4*)(muW + (size_t)zi * HID);
        const float4* pq = (const float4*)(lvW + (size_t)zi * HID);
        const float4* ph = (const float4*)(&hfp[zrow][0]);
        #pragma unroll
        for (int q = 0; q < 16; ++q){
            float4 wm = pm[q], wl = pq[q], hv = ph[q];
            am += wm.x*hv.x + wm.y*hv.y + wm.z*hv.z + wm.w*hv.w;
            al += wl.x*hv.x + wl.y*hv.y + wl.z*hv.z + wl.w*hv.w;
        }
        const size_t muBase = (size_t)B_TOTAL * T_LEN;
        out[muBase + (size_t)(b0 + zrow) * LAT + zi] = am;
        out[muBase + (size_t)B_TOTAL * LAT + (size_t)(b0 + zrow) * LAT + zi] = al;
        z0v = am + __expf(0.5f * al);
    }

    // ================= ODE: RK4, 24 fixed steps on [0,1] =================
    if (tid < ROWS * LAT){
        float ows[16];
        {
            const float4* pw = (const float4*)(oW + (size_t)zi * LAT);
            #pragma unroll
            for (int q = 0; q < 4; ++q){
                float4 w = pw[q];
                ows[4*q+0] = w.x; ows[4*q+1] = w.y; ows[4*q+2] = w.z; ows[4*q+3] = w.w;
            }
        }
        const float obv = ob[zi];
        float z = z0v;
        const float hstep = 1.0f / 24.0f;
        for (int s = 0; s < 24; ++s){
            float y, k1, k2, k3, k4;
            y = z;
            { float acc = obv;
              #pragma unroll
              for (int jj = 0; jj < 16; ++jj){ float yj = __shfl(y, jj, 16); acc = fmaf(ows[jj], yj, acc); }
              k1 = fmaxf(acc, 0.0f); }
            y = z + 0.5f * hstep * k1;
            { float acc = obv;
              #pragma unroll
              for (int jj = 0; jj < 16; ++jj){ float yj = __shfl(y, jj, 16); acc = fmaf(ows[jj], yj, acc); }
              k2 = fmaxf(acc, 0.0f); }
            y = z + 0.5f * hstep * k2;
            { float acc = obv;
              #pragma unroll
              for (int jj = 0; jj < 16; ++jj){ float yj = __shfl(y, jj, 16); acc = fmaf(ows[jj], yj, acc); }
              k3 = fmaxf(acc, 0.0f); }
            y = z + hstep * k3;
            { float acc = obv;
              #pragma unroll
              for (int jj = 0; jj < 16; ++jj){ float yj = __shfl(y, jj, 16); acc = fmaf(ows[jj], yj, acc); }
              k4 = fmaxf(acc, 0.0f); }
            z += (hstep / 6.0f) * (k1 + 2.0f*k2 + 2.0f*k3 + k4);
        }
        zsh[zrow][zi] = z;
    }
    __syncthreads();

    // ================= decoder fc: zd = relu(z @ dfW.T + dfb) =================
    for (int idx = tid; idx < ROWS * HID; idx += THREADS){
        const int row = idx >> 6, o = idx & 63;
        float acc = dfb[o];
        const float4* pw = (const float4*)(dfW + (size_t)o * LAT);
        const float4* pz = (const float4*)(&zsh[row][0]);
        #pragma unroll
        for (int q = 0; q < 4; ++q){
            float4 w = pw[q], zv = pz[q];
            acc += w.x*zv.x + w.y*zv.y + w.z*zv.z + w.w*zv.w;
        }
        zdsh[row][o] = fmaxf(acc, 0.0f);
    }
    __syncthreads();

    // xg_dec = zd @ dec_Wih.T + dec_bih
    if (tid < ROWS * 3){
        const int row = tid / 3, gg = tid % 3;
        float acc = dbih[gg];
        const float4* pw = (const float4*)(dWih + (size_t)gg * HID);
        const float4* pz = (const float4*)(&zdsh[row][0]);
        #pragma unroll
        for (int q = 0; q < 16; ++q){
            float4 w = pw[q], zv = pz[q];
            acc += w.x*zv.x + w.y*zv.y + w.z*zv.z + w.w*zv.w;
        }
        xgdsh[row][gg] = acc;
    }
    __syncthreads();

    // ====== decoder GRU (hidden dim 1), 512 steps, direct float4 global stores ===
    if (tid < ROWS){
        const int row = tid;
        const float xr = xgdsh[row][0], xz = xgdsh[row][1], xn = xgdsh[row][2];
        const float A0 = dWhh[0], A1 = dWhh[1], A2 = dWhh[2];
        const float c0 = dbhh[0], c1 = dbhh[1], c2 = dbhh[2];
        float* orow = out + (size_t)(b0 + row) * T_LEN;   // 16B-aligned
        float h = 0.0f;
        float ob4[4];
        for (int t = 0; t < T_LEN; ++t){
            float rr = fast_sigmoid(xr + A0 * h + c0);
            float zz = fast_sigmoid(xz + A1 * h + c1);
            float nn = fast_tanh(xn + rr * (A2 * h + c2));
            h = (1.0f - zz) * nn + zz * h;
            ob4[t & 3] = h;
            if ((t & 3) == 3) *(float4*)(orow + (t - 3)) = *(float4*)ob4;
        }
    }
}

extern "C" void kernel_launch(void* const* d_in, const int* in_sizes, int n_in,
                              void* d_out, int out_size, void* d_ws, size_t ws_size,
                              hipStream_t stream){
    glsde_kernel<<<B_TOTAL / ROWS, THREADS, 0, stream>>>(
        (const float*)d_in[0],  (const float*)d_in[1],  (const float*)d_in[2],
        (const float*)d_in[3],  (const float*)d_in[4],  (const float*)d_in[5],
        (const float*)d_in[6],  (const float*)d_in[7],  (const float*)d_in[8],
        (const float*)d_in[9],  (const float*)d_in[10], (const float*)d_in[11],
        (const float*)d_in[12], (const float*)d_in[13], (const float*)d_in[14],
        (const float*)d_in[15], (const float*)d_in[16], (float*)d_out);
}